// Round 6
// baseline (355.567 us; speedup 1.0000x reference)
//
#include <hip/hip_runtime.h>

// Problem constants (fixed shapes)
#define BB 8192      // batch
#define DZ 1024
#define DS 64
#define DH 4096
#define KEXT (DH + DS)   // 4160: K of GEMM2 = [H | s]

typedef float floatx4 __attribute__((ext_vector_type(4)));
typedef __bf16 bf16x8 __attribute__((ext_vector_type(8)));
typedef __bf16 bf16x4 __attribute__((ext_vector_type(4)));
typedef __attribute__((address_space(1))) void* as1_void_ptr;
typedef __attribute__((address_space(3))) void* as3_void_ptr;

// s_waitcnt immediates (gfx9: vmcnt[3:0] bits0-3 + [5:4] bits15:14,
// expcnt bits6:4, lgkmcnt bits11:8). lgkm=15,exp=7 "unconstrained" base = 3952.
#define WAIT_VM0   3952   // vmcnt(0)
#define WAIT_VM6   3958   // vmcnt(6)
#define WAIT_LGKM0 49279  // lgkmcnt(0), vm/exp unconstrained

__device__ __forceinline__ void async_copy16(const void* g, void* l) {
    // global -> LDS direct copy, 16B/lane; per-lane GLOBAL address,
    // wave-uniform LDS base + lane*16 dest.
    __builtin_amdgcn_global_load_lds((as1_void_ptr)g, (as3_void_ptr)l, 16, 0, 0);
}

__device__ __forceinline__ bf16x8 cvt8(float4 a, float4 b) {
    bf16x8 o = { (__bf16)a.x, (__bf16)a.y, (__bf16)a.z, (__bf16)a.w,
                 (__bf16)b.x, (__bf16)b.y, (__bf16)b.z, (__bf16)b.w };
    return o;
}

// LDS bank-conflict swizzle (VERIFIED round 1: SQ_LDS_BANK_CONFLICT 8.5M -> 0):
// Panels are [rows x 32] bf16 row-major => 64B row stride. Swizzle 16B chunks
// within each row: physical chunk p holds K-chunk p ^ ((row>>1)&3).
// gload_lds path: staging thread t (row t>>2) loads global chunk
// (t&3)^((t>>3)&3). Reg-staged path (gemm1 A, round 5): thread writes
// K-chunk c at physical c^((row>>1)&3) via ds_write_b128 -- produces the
// same LDS image. Read side: chunk = (lane>>4) ^ ((lane>>1)&3).
// Write-conflict check: slot(l) = ((row&1)*4 + pchunk) mod 8; 64 lanes ->
// 8 slots x 8 lanes = exactly the inherent 8-beat occupancy of a wave64
// b128 access -> balanced, conflict-free.

// ---------------- prep: streaming f32->bf16 repack ----------------
// Round 5: z/zb branch REMOVED (z fused into gemm1 + gemm2 epilogue).
// Remaining traffic: W1 (16+8), B2b (16.25+8.3), s (2+1) ~= 52 MB
// (was ~100 MB). Decisive for the prep anomaly: rate-model predicts
// prep ~45us; fixed-overhead-model predicts no change.
__global__ __launch_bounds__(256) void prep_all(
    const float* __restrict__ W1, const float* __restrict__ W2,
    const float* __restrict__ C, const float* __restrict__ s,
    __bf16* __restrict__ W1b, __bf16* __restrict__ B2b,
    __bf16* __restrict__ Hb)
{
    constexpr int NC_W1 = (DH * DZ) / 8;          // 524288
    constexpr int NC_B2 = (DZ * KEXT) / 8;        // 532480 (1024 rows x 520)
    constexpr int NC_S  = (BB * DS) / 8;          // 65536
    constexpr int NC_TOT = NC_W1 + NC_B2 + NC_S;
    const int stride = gridDim.x * blockDim.x;
    for (int c = blockIdx.x * blockDim.x + threadIdx.x; c < NC_TOT; c += stride) {
        const float4* src;
        __bf16* dst;
        if (c < NC_W1) {
            src = (const float4*)W1 + (size_t)c * 2;
            dst = W1b + (size_t)c * 8;
        } else if (c < NC_W1 + NC_B2) {
            int i = c - NC_W1;
            int j = i / 520, p = i - j * 520;     // row j of B2b, chunk p
            int h = p * 8;
            const float* sp = (h < DH) ? (W2 + (size_t)j * DH + h)
                                       : (C  + (size_t)j * DS + (h - DH));
            src = (const float4*)sp;
            dst = B2b + (size_t)j * KEXT + h;
        } else {
            int i = c - (NC_W1 + NC_B2);
            int r = i >> 3, k = (i & 7) * 8;      // row r of s, 8-elem chunk
            src = (const float4*)(s + (size_t)r * DS + k);
            dst = Hb + (size_t)r * KEXT + DH + k;
        }
        float4 a = src[0], b = src[1];
        *(bf16x8*)dst = cvt8(a, b);
    }
}

// ---------------- GEMM1: Hb[:, :4096] = relu(z @ W1b^T + h1) ----------------
// A = z [8192 x 1024] FP32 (fused conversion: reg-stage 2x float4 -> cvt ->
// ds_write_b128 into the verified swizzled panel layout). B = W1b bf16 via
// global_load_lds (unchanged). BK=64, single-buffer, 48 KB LDS,
// target VGPR <= 128 (2 blocks/CU).
__global__ __launch_bounds__(512, 4) void gemm1_relu(
    const float* __restrict__ Az, const __bf16* __restrict__ Bg,
    const float* __restrict__ h1, __bf16* __restrict__ Hb)
{
    constexpr int ldB = DZ, KITER = DZ / 64;
    __shared__ __align__(16) __bf16 As[256 * 64];   // 32 KB (2 panels of 256x32)
    __shared__ __align__(16) __bf16 Bs[128 * 64];   // 16 KB (2 panels of 128x32)

    const int tid = threadIdx.x;
    const int wave = tid >> 6, lane = tid & 63;
    const int wm = wave >> 1, wn = wave & 1;
    const int row0 = blockIdx.x * 256;
    const int col0 = blockIdx.y * 128;

    // A reg-staging: thread t -> row r = t>>1 (0..255), K-half h = t&1.
    // Loads 32 f32 of z[row0+r][kt*64 + h*32 ..], writes 4 swizzled 16B
    // chunks into panel h, row r.
    const float* az = Az + (size_t)(row0 + (tid >> 1)) * DZ + (tid & 1) * 32;
    __bf16* aw = As + (tid & 1) * 8192 + (tid >> 1) * 32;
    const int rsw = (tid >> 2) & 3;                 // (r>>1)&3, r = tid>>1

    // B staging via gload_lds (verified involution source swizzle)
    const int csrc = ((tid & 3) ^ ((tid >> 3) & 3)) * 8;
    const __bf16* pB = Bg + (size_t)(col0 + (tid >> 2)) * ldB + csrc;
    __bf16* lB = Bs + wave * 512;

    const int cswz = ((lane >> 4) ^ ((lane >> 1) & 3)) * 8; // swizzled read chunk
    const __bf16* Afrag = As + (wm * 64 + (lane & 15)) * 32 + cswz;
    const __bf16* Bfrag = Bs + (wn * 64 + (lane & 15)) * 32 + cswz;

    floatx4 acc[4][4];
#pragma unroll
    for (int i = 0; i < 4; ++i)
#pragma unroll
        for (int j = 0; j < 4; ++j) acc[i][j] = (floatx4)0.0f;

    for (int kt = 0; kt < KITER; ++kt) {
        // B: 128 rows, panels k+0 / k+32 (async, direct to LDS)
        const __bf16* bk = pB + kt * 64;
        async_copy16(bk,      lB);
        async_copy16(bk + 32, lB + 4096);
        // A: f32 -> bf16 reg-staged into swizzled panels
        const float* zk = az + kt * 64;
#pragma unroll
        for (int c = 0; c < 4; ++c) {
            float4 a = *(const float4*)(zk + c * 8);
            float4 b = *(const float4*)(zk + c * 8 + 4);
            *(bf16x8*)(aw + ((c ^ rsw) << 3)) = cvt8(a, b);
        }
        __builtin_amdgcn_s_waitcnt(0);
        __syncthreads();

#pragma unroll
        for (int ks = 0; ks < 2; ++ks) {
            bf16x8 af[4], bfr[4];
#pragma unroll
            for (int i = 0; i < 4; ++i) af[i] = *(const bf16x8*)(Afrag + ks * 8192 + i * 16 * 32);
#pragma unroll
            for (int j = 0; j < 4; ++j) bfr[j] = *(const bf16x8*)(Bfrag + ks * 4096 + j * 16 * 32);
#pragma unroll
            for (int i = 0; i < 4; ++i)
#pragma unroll
                for (int j = 0; j < 4; ++j)
                    acc[i][j] = __builtin_amdgcn_mfma_f32_16x16x32_bf16(af[i], bfr[j], acc[i][j], 0, 0, 0);
        }
        __syncthreads();
    }

    // epilogue: C/D layout col = lane&15, row = (lane>>4)*4 + reg
    const int r0 = row0 + wm * 64 + (lane >> 4) * 4;
    const int c0 = col0 + wn * 64 + (lane & 15);
#pragma unroll
    for (int i = 0; i < 4; ++i) {
#pragma unroll
        for (int j = 0; j < 4; ++j) {
            int c = c0 + j * 16;
            float bias = h1[c];
#pragma unroll
            for (int rg = 0; rg < 4; ++rg) {
                int r = r0 + i * 16 + rg;
                float v = acc[i][j][rg] + bias;
                v = v > 0.0f ? v : 0.0f;
                Hb[(size_t)r * KEXT + c] = (__bf16)v;
            }
        }
    }
}

// ---------------- GEMM2: out = Hb @ B2b^T + A*z + h2 ----------------
// A = Hb [8192 x 4160] K-major, B = B2b [1024 x 4160] K-major. BK=64.
// Grid = 32x8 = 256 blocks = exactly 1/CU -> explicit dbuf raw-barrier
// pipeline (96 KB LDS). Round 5: epilogue reads z as f32 directly
// (zb eliminated); GEMM core unchanged.
__global__ __launch_bounds__(512, 2) void gemm2_out(
    const __bf16* __restrict__ Ag, const __bf16* __restrict__ Bg,
    const float* __restrict__ Adiag, const float* __restrict__ h2,
    const float* __restrict__ z, float* __restrict__ out)
{
    constexpr int ldA = KEXT, ldB = KEXT, KITER = KEXT / 64;
    __shared__ __align__(16) __bf16 As[2 * 256 * 64];   // 64 KB dbuf
    __shared__ __align__(16) __bf16 Bs[2 * 128 * 64];   // 32 KB dbuf

    const int tid = threadIdx.x;
    const int wave = tid >> 6, lane = tid & 63;
    const int wm = wave >> 1, wn = wave & 1;
    const int row0 = blockIdx.x * 256;
    const int col0 = blockIdx.y * 128;

    const int csrc = ((tid & 3) ^ ((tid >> 3) & 3)) * 8;   // swizzled src chunk
    const __bf16* pA = Ag + (size_t)(row0 + (tid >> 2)) * ldA + csrc;
    const __bf16* pB = Bg + (size_t)(col0 + ((tid >> 2) & 127)) * ldB + csrc;

    const int cswz = ((lane >> 4) ^ ((lane >> 1) & 3)) * 8; // swizzled read chunk
    const __bf16* Afrag = As + (wm * 64 + (lane & 15)) * 32 + cswz;
    const __bf16* Bfrag = Bs + (wn * 64 + (lane & 15)) * 32 + cswz;

    floatx4 acc[4][4];
#pragma unroll
    for (int i = 0; i < 4; ++i)
#pragma unroll
        for (int j = 0; j < 4; ++j) acc[i][j] = (floatx4)0.0f;

    // issue tile kt into buffer q (6 copies)
    auto issue = [&](int kt, int q) {
        const __bf16* ak = pA + kt * 64;
        const __bf16* bk = pB + kt * 64;
        __bf16* lA = As + q * 16384 + wave * 512;
        __bf16* lB = Bs + q * 8192  + wave * 512;
        async_copy16(ak,                           lA);
        async_copy16(ak + (size_t)128 * ldA,       lA + 4096);
        async_copy16(ak + 32,                      lA + 8192);
        async_copy16(ak + (size_t)128 * ldA + 32,  lA + 8192 + 4096);
        async_copy16(bk,                           lB);
        async_copy16(bk + 32,                      lB + 4096);
    };

    issue(0, 0);   // prologue

    for (int kt = 0; kt < KITER; ++kt) {
        const int p = kt & 1;
        if (kt + 1 < KITER) {
            issue(kt + 1, p ^ 1);
            __builtin_amdgcn_s_waitcnt(WAIT_VM6);   // prior tile's 6 done; 6 in flight
        } else {
            __builtin_amdgcn_s_waitcnt(WAIT_VM0);
        }
        __builtin_amdgcn_s_barrier();

#pragma unroll
        for (int ks = 0; ks < 2; ++ks) {
            const __bf16* Ab = Afrag + p * 16384 + ks * 8192;
            const __bf16* Bb = Bfrag + p * 8192  + ks * 4096;
            bf16x8 af[4], bfr[4];
#pragma unroll
            for (int i = 0; i < 4; ++i) af[i] = *(const bf16x8*)(Ab + i * 16 * 32);
#pragma unroll
            for (int j = 0; j < 4; ++j) bfr[j] = *(const bf16x8*)(Bb + j * 16 * 32);
#pragma unroll
            for (int i = 0; i < 4; ++i)
#pragma unroll
                for (int j = 0; j < 4; ++j)
                    acc[i][j] = __builtin_amdgcn_mfma_f32_16x16x32_bf16(af[i], bfr[j], acc[i][j], 0, 0, 0);
        }

        __builtin_amdgcn_s_waitcnt(WAIT_LGKM0);     // reads of buf p done
        __builtin_amdgcn_s_barrier();               // safe to refill buf p
    }

    const int r0 = row0 + wm * 64 + (lane >> 4) * 4;
    const int c0 = col0 + wn * 64 + (lane & 15);
#pragma unroll
    for (int i = 0; i < 4; ++i) {
#pragma unroll
        for (int j = 0; j < 4; ++j) {
            const int c = c0 + j * 16;
            const float aj = Adiag[c];
            const float hj = h2[c];
#pragma unroll
            for (int rg = 0; rg < 4; ++rg) {
                const int r = r0 + i * 16 + rg;
                out[(size_t)r * DZ + c] =
                    acc[i][j][rg] + aj * z[(size_t)r * DZ + c] + hj;
            }
        }
    }
}

// ---------------- launch ----------------

extern "C" void kernel_launch(void* const* d_in, const int* in_sizes, int n_in,
                              void* d_out, int out_size, void* d_ws, size_t ws_size,
                              hipStream_t stream) {
    const float* z  = (const float*)d_in[0];   // [8192,1024]
    const float* s  = (const float*)d_in[1];   // [8192,64]
    const float* A  = (const float*)d_in[2];   // [1024]
    const float* W1 = (const float*)d_in[3];   // [4096,1024]
    const float* W2 = (const float*)d_in[4];   // [1024,4096]
    const float* h1 = (const float*)d_in[5];   // [4096]
    const float* h2 = (const float*)d_in[6];   // [1024]
    const float* C  = (const float*)d_in[7];   // [1024,64]
    float* out = (float*)d_out;

    // workspace layout (bytes): Hb | W1b | B2b  (zb ELIMINATED, round 5)
    char* ws = (char*)d_ws;
    size_t offHb  = 0;
    size_t offW1b = offHb  + (size_t)BB * KEXT * 2;
    size_t offB2b = offW1b + (size_t)DH * DZ * 2;
    __bf16* Hb  = (__bf16*)(ws + offHb);    // [8192 x 4160]
    __bf16* W1b = (__bf16*)(ws + offW1b);   // [4096 x 1024]
    __bf16* B2b = (__bf16*)(ws + offB2b);   // [1024 x 4160] = [W2 | C]

    prep_all<<<2048, 256, 0, stream>>>(W1, W2, C, s, W1b, B2b, Hb);
    gemm1_relu<<<dim3(BB / 256, DH / 128), 512, 0, stream>>>(z, W1b, h1, Hb);
    gemm2_out<<<dim3(BB / 256, DZ / 128), 512, 0, stream>>>(Hb, B2b, A, h2, z, out);
}

// Round 7
// 250.803 us; speedup vs baseline: 1.4177x; 1.4177x over previous
//
#include <hip/hip_runtime.h>

// Problem constants (fixed shapes)
#define BB 8192      // batch
#define DZ 1024
#define DS 64
#define DH 4096
#define KEXT (DH + DS)   // 4160: K of GEMM2 = [H | s]

typedef float floatx4 __attribute__((ext_vector_type(4)));
typedef __bf16 bf16x8 __attribute__((ext_vector_type(8)));
typedef __bf16 bf16x4 __attribute__((ext_vector_type(4)));
typedef __attribute__((address_space(1))) void* as1_void_ptr;
typedef __attribute__((address_space(3))) void* as3_void_ptr;

// s_waitcnt immediates (gfx9: vmcnt[3:0] bits0-3 + [5:4] bits15:14,
// expcnt bits6:4, lgkmcnt bits11:8). lgkm=15,exp=7 "unconstrained" base = 3952.
#define WAIT_VM0   3952   // vmcnt(0)
#define WAIT_VM8   3960   // vmcnt(8)
#define WAIT_LGKM0 49279  // lgkmcnt(0), vm/exp unconstrained

__device__ __forceinline__ void async_copy16(const void* g, void* l) {
    // global -> LDS direct copy, 16B/lane; per-lane GLOBAL address,
    // wave-uniform LDS base + lane*16 dest.
    __builtin_amdgcn_global_load_lds((as1_void_ptr)g, (as3_void_ptr)l, 16, 0, 0);
}

__device__ __forceinline__ bf16x4 cvt4(float4 v) {
    bf16x4 o = { (__bf16)v.x, (__bf16)v.y, (__bf16)v.z, (__bf16)v.w };
    return o;
}

__device__ __forceinline__ bf16x8 cvt8(float4 a, float4 b) {
    bf16x8 o = { (__bf16)a.x, (__bf16)a.y, (__bf16)a.z, (__bf16)a.w,
                 (__bf16)b.x, (__bf16)b.y, (__bf16)b.z, (__bf16)b.w };
    return o;
}

// LDS bank-conflict swizzle (VERIFIED round 1: SQ_LDS_BANK_CONFLICT 8.5M -> 0):
// Panels are [rows x 32] bf16 row-major => 64B row stride. Swizzle 16B chunks
// within each row: physical chunk p holds K-chunk p ^ ((row>>1)&3).
// gload_lds path: staging thread t (row t>>2, phys chunk t&3) loads global
// chunk (t&3)^((t>>3)&3). Read side: chunk = (lane>>4) ^ ((lane>>1)&3).
//
// SESSION LEDGER (counter-verified):
//   R1: swizzle -> conflicts 8.5M->0. Timing-null on gemm2 (1/CU lockstep,
//       stalls hidden); real on gemm1 (3/CU, LDS on critical path).
//   R3: gemm2 BK=32 split + setprio: REGRESSED (2x kt overhead; setprio
//       starves co-resident staging waves in barrier-synced GEMM).
//   R6: f32-A reg-staging in gemm1: REGRESSED 75->182us (latency chain +
//       2x staged bytes + HBM refetch). zb via prep is the right form.
//   R1/R4/R6 prep sweep: prep is BW-bound (~16us @100MB); ~75us/iter is
//       FIXED harness overhead (reset dispatches) -- not addressable.
//       Controllable budget = gemm1 + gemm2 kernel time only.

// ---------------- prep: streaming f32->bf16 repack ----------------
// Grid-stride, 8-elem chunks (2x float4 -> 1x 16B bf16x8 store).
// zb restored (R6 lesson: GEMM A-operand must be pre-converted bf16).
__global__ __launch_bounds__(256) void prep_all(
    const float* __restrict__ z, const float* __restrict__ W1,
    const float* __restrict__ W2, const float* __restrict__ C,
    const float* __restrict__ s,
    __bf16* __restrict__ zb, __bf16* __restrict__ W1b,
    __bf16* __restrict__ B2b, __bf16* __restrict__ Hb)
{
    constexpr int NC_Z  = (BB * DZ) / 8;          // 1048576
    constexpr int NC_W1 = (DH * DZ) / 8;          // 524288
    constexpr int NC_B2 = (DZ * KEXT) / 8;        // 532480 (1024 rows x 520)
    constexpr int NC_S  = (BB * DS) / 8;          // 65536
    constexpr int NC_TOT = NC_Z + NC_W1 + NC_B2 + NC_S;
    const int stride = gridDim.x * blockDim.x;
    for (int c = blockIdx.x * blockDim.x + threadIdx.x; c < NC_TOT; c += stride) {
        const float4* src;
        __bf16* dst;
        if (c < NC_Z) {
            src = (const float4*)z + (size_t)c * 2;
            dst = zb + (size_t)c * 8;
        } else if (c < NC_Z + NC_W1) {
            int i = c - NC_Z;
            src = (const float4*)W1 + (size_t)i * 2;
            dst = W1b + (size_t)i * 8;
        } else if (c < NC_Z + NC_W1 + NC_B2) {
            int i = c - (NC_Z + NC_W1);
            int j = i / 520, p = i - j * 520;     // row j of B2b, chunk p
            int h = p * 8;
            const float* sp = (h < DH) ? (W2 + (size_t)j * DH + h)
                                       : (C  + (size_t)j * DS + (h - DH));
            src = (const float4*)sp;
            dst = B2b + (size_t)j * KEXT + h;
        } else {
            int i = c - (NC_Z + NC_W1 + NC_B2);
            int r = i >> 3, k = (i & 7) * 8;      // row r of s, 8-elem chunk
            src = (const float4*)(s + (size_t)r * DS + k);
            dst = Hb + (size_t)r * KEXT + DH + k;
        }
        float4 a = src[0], b = src[1];
        *(bf16x8*)dst = cvt8(a, b);
    }
}

// ---------------- GEMM1: Hb[:, :4096] = relu(zb @ W1b^T + h1) ----------------
// R4-PROVEN FORM (restored verbatim): A = zb bf16 via gload_lds, BK=64,
// single-buffer, 48 KB LDS, 88 VGPR -> 3 blocks/CU; cross-block overlap is
// the pipeline. ~75us = 921 TF = this structure's ceiling (m97).
__global__ __launch_bounds__(512, 4) void gemm1_relu(
    const __bf16* __restrict__ Ag, const __bf16* __restrict__ Bg,
    const float* __restrict__ h1, __bf16* __restrict__ Hb)
{
    constexpr int ldA = DZ, ldB = DZ, KITER = DZ / 64;
    __shared__ __align__(16) __bf16 As[256 * 64];   // 32 KB (2 panels of 256x32)
    __shared__ __align__(16) __bf16 Bs[128 * 64];   // 16 KB (2 panels of 128x32)

    const int tid = threadIdx.x;
    const int wave = tid >> 6, lane = tid & 63;
    const int wm = wave >> 1, wn = wave & 1;
    const int row0 = blockIdx.x * 256;
    const int col0 = blockIdx.y * 128;

    const int csrc = ((tid & 3) ^ ((tid >> 3) & 3)) * 8;   // swizzled src chunk
    const __bf16* pA = Ag + (size_t)(row0 + (tid >> 2)) * ldA + csrc;
    const __bf16* pB = Bg + (size_t)(col0 + ((tid >> 2) & 127)) * ldB + csrc;
    __bf16* lA = As + wave * 512;   // + lane*16B implicit (8 waves cover 128 rows)
    __bf16* lB = Bs + wave * 512;

    const int cswz = ((lane >> 4) ^ ((lane >> 1) & 3)) * 8; // swizzled read chunk
    const __bf16* Afrag = As + (wm * 64 + (lane & 15)) * 32 + cswz;
    const __bf16* Bfrag = Bs + (wn * 64 + (lane & 15)) * 32 + cswz;

    floatx4 acc[4][4];
#pragma unroll
    for (int i = 0; i < 4; ++i)
#pragma unroll
        for (int j = 0; j < 4; ++j) acc[i][j] = (floatx4)0.0f;

    for (int kt = 0; kt < KITER; ++kt) {
        const __bf16* ak = pA + kt * 64;
        const __bf16* bk = pB + kt * 64;
        // A: rows 0-127 / 128-255, panels k+0 / k+32
        async_copy16(ak,                           lA);
        async_copy16(ak + (size_t)128 * ldA,       lA + 4096);
        async_copy16(ak + 32,                      lA + 8192);
        async_copy16(ak + (size_t)128 * ldA + 32,  lA + 8192 + 4096);
        // B: 128 rows, panels k+0 / k+32
        async_copy16(bk,                           lB);
        async_copy16(bk + 32,                      lB + 4096);
        __builtin_amdgcn_s_waitcnt(0);
        __syncthreads();

#pragma unroll
        for (int ks = 0; ks < 2; ++ks) {
            bf16x8 af[4], bfr[4];
#pragma unroll
            for (int i = 0; i < 4; ++i) af[i] = *(const bf16x8*)(Afrag + ks * 8192 + i * 16 * 32);
#pragma unroll
            for (int j = 0; j < 4; ++j) bfr[j] = *(const bf16x8*)(Bfrag + ks * 4096 + j * 16 * 32);
#pragma unroll
            for (int i = 0; i < 4; ++i)
#pragma unroll
                for (int j = 0; j < 4; ++j)
                    acc[i][j] = __builtin_amdgcn_mfma_f32_16x16x32_bf16(af[i], bfr[j], acc[i][j], 0, 0, 0);
        }
        __syncthreads();
    }

    // epilogue: C/D layout col = lane&15, row = (lane>>4)*4 + reg
    const int r0 = row0 + wm * 64 + (lane >> 4) * 4;
    const int c0 = col0 + wn * 64 + (lane & 15);
#pragma unroll
    for (int i = 0; i < 4; ++i) {
#pragma unroll
        for (int j = 0; j < 4; ++j) {
            int c = c0 + j * 16;
            float bias = h1[c];
#pragma unroll
            for (int rg = 0; rg < 4; ++rg) {
                int r = r0 + i * 16 + rg;
                float v = acc[i][j][rg] + bias;
                v = v > 0.0f ? v : 0.0f;
                Hb[(size_t)r * KEXT + c] = (__bf16)v;
            }
        }
    }
}

// ---------------- GEMM2: out = Hb @ B2b^T + A*z + h2 ----------------
// ROUND 7 RESTRUCTURE: 128x128 tile, 4 waves (256 thr) of 64x64, BK=64,
// dbuf 64 KB LDS -> grid 64x8 = 512 blocks = 2 blocks/CU. Mechanism:
// gemm2 does the same FLOP as gemm1 but ran 18% slower at 1 block/CU
// lockstep; 2 independent blocks/CU desynchronize (gemm1's proven regime)
// AND the counted-vmcnt dbuf pipeline is kept (8 copies/kt -> vmcnt(8)).
// Unlike R3's failed split: BK stays 64 (kt count unchanged), no setprio.
// Grid order x-fastest: consecutive blocks share the B col-panel (1 MB,
// L2-resident per XCD); Hb row-panels also land on one XCD (bid%8 = bx%8).
__global__ __launch_bounds__(256, 2) void gemm2_out(
    const __bf16* __restrict__ Ag, const __bf16* __restrict__ Bg,
    const float* __restrict__ Adiag, const float* __restrict__ h2,
    const float* __restrict__ z, float* __restrict__ out)
{
    constexpr int ldA = KEXT, ldB = KEXT, KITER = KEXT / 64;   // 65
    __shared__ __align__(16) __bf16 As[2 * 128 * 64];   // 32 KB dbuf
    __shared__ __align__(16) __bf16 Bs[2 * 128 * 64];   // 32 KB dbuf

    const int tid = threadIdx.x;
    const int wave = tid >> 6, lane = tid & 63;
    const int wm = wave >> 1, wn = wave & 1;            // 2x2 waves of 64x64
    const int row0 = blockIdx.x * 128;
    const int col0 = blockIdx.y * 128;

    const int csrc = ((tid & 3) ^ ((tid >> 3) & 3)) * 8;   // swizzled src chunk
    const __bf16* pA = Ag + (size_t)(row0 + (tid >> 2)) * ldA + csrc;   // rows 0..63
    const __bf16* pB = Bg + (size_t)(col0 + (tid >> 2)) * ldB + csrc;

    const int cswz = ((lane >> 4) ^ ((lane >> 1) & 3)) * 8; // swizzled read chunk
    const __bf16* Afrag = As + (wm * 64 + (lane & 15)) * 32 + cswz;
    const __bf16* Bfrag = Bs + (wn * 64 + (lane & 15)) * 32 + cswz;

    floatx4 acc[4][4];
#pragma unroll
    for (int i = 0; i < 4; ++i)
#pragma unroll
        for (int j = 0; j < 4; ++j) acc[i][j] = (floatx4)0.0f;

    // issue tile kt into buffer q: 8 copies of 4KB (256 thr x 16B).
    // A: rows 0-63 / 64-127 x panels k+0 / k+32; B same. Panel layout
    // [panel][128 rows][32], panel stride 4096 elems, dbuf stride 8192.
    auto issue = [&](int kt, int q) {
        const __bf16* ak = pA + kt * 64;
        const __bf16* bk = pB + kt * 64;
        __bf16* lA = As + q * 8192 + wave * 512;
        __bf16* lB = Bs + q * 8192 + wave * 512;
        async_copy16(ak,                          lA);
        async_copy16(ak + (size_t)64 * ldA,       lA + 2048);
        async_copy16(ak + 32,                     lA + 4096);
        async_copy16(ak + (size_t)64 * ldA + 32,  lA + 4096 + 2048);
        async_copy16(bk,                          lB);
        async_copy16(bk + (size_t)64 * ldB,       lB + 2048);
        async_copy16(bk + 32,                     lB + 4096);
        async_copy16(bk + (size_t)64 * ldB + 32,  lB + 4096 + 2048);
    };

    issue(0, 0);   // prologue

    for (int kt = 0; kt < KITER; ++kt) {
        const int p = kt & 1;
        if (kt + 1 < KITER) {
            issue(kt + 1, p ^ 1);
            __builtin_amdgcn_s_waitcnt(WAIT_VM8);   // tile kt's 8 done; 8 in flight
        } else {
            __builtin_amdgcn_s_waitcnt(WAIT_VM0);
        }
        __builtin_amdgcn_s_barrier();

#pragma unroll
        for (int ks = 0; ks < 2; ++ks) {
            const __bf16* Ab = Afrag + p * 8192 + ks * 4096;
            const __bf16* Bb = Bfrag + p * 8192 + ks * 4096;
            bf16x8 af[4], bfr[4];
#pragma unroll
            for (int i = 0; i < 4; ++i) af[i] = *(const bf16x8*)(Ab + i * 16 * 32);
#pragma unroll
            for (int j = 0; j < 4; ++j) bfr[j] = *(const bf16x8*)(Bb + j * 16 * 32);
#pragma unroll
            for (int i = 0; i < 4; ++i)
#pragma unroll
                for (int j = 0; j < 4; ++j)
                    acc[i][j] = __builtin_amdgcn_mfma_f32_16x16x32_bf16(af[i], bfr[j], acc[i][j], 0, 0, 0);
        }

        __builtin_amdgcn_s_waitcnt(WAIT_LGKM0);     // reads of buf p done
        __builtin_amdgcn_s_barrier();               // safe to refill buf p
    }

    const int r0 = row0 + wm * 64 + (lane >> 4) * 4;
    const int c0 = col0 + wn * 64 + (lane & 15);
#pragma unroll
    for (int i = 0; i < 4; ++i) {
#pragma unroll
        for (int j = 0; j < 4; ++j) {
            const int c = c0 + j * 16;
            const float aj = Adiag[c];
            const float hj = h2[c];
#pragma unroll
            for (int rg = 0; rg < 4; ++rg) {
                const int r = r0 + i * 16 + rg;
                out[(size_t)r * DZ + c] =
                    acc[i][j][rg] + aj * z[(size_t)r * DZ + c] + hj;
            }
        }
    }
}

// ---------------- launch ----------------

extern "C" void kernel_launch(void* const* d_in, const int* in_sizes, int n_in,
                              void* d_out, int out_size, void* d_ws, size_t ws_size,
                              hipStream_t stream) {
    const float* z  = (const float*)d_in[0];   // [8192,1024]
    const float* s  = (const float*)d_in[1];   // [8192,64]
    const float* A  = (const float*)d_in[2];   // [1024]
    const float* W1 = (const float*)d_in[3];   // [4096,1024]
    const float* W2 = (const float*)d_in[4];   // [1024,4096]
    const float* h1 = (const float*)d_in[5];   // [4096]
    const float* h2 = (const float*)d_in[6];   // [1024]
    const float* C  = (const float*)d_in[7];   // [1024,64]
    float* out = (float*)d_out;

    // workspace layout (bytes): Hb | zb | W1b | B2b  ~= 102 MB total
    char* ws = (char*)d_ws;
    size_t offHb  = 0;
    size_t offZb  = offHb  + (size_t)BB * KEXT * 2;
    size_t offW1b = offZb  + (size_t)BB * DZ * 2;
    size_t offB2b = offW1b + (size_t)DH * DZ * 2;
    __bf16* Hb  = (__bf16*)(ws + offHb);    // [8192 x 4160]
    __bf16* zb  = (__bf16*)(ws + offZb);    // [8192 x 1024]
    __bf16* W1b = (__bf16*)(ws + offW1b);   // [4096 x 1024]
    __bf16* B2b = (__bf16*)(ws + offB2b);   // [1024 x 4160] = [W2 | C]

    prep_all<<<2048, 256, 0, stream>>>(z, W1, W2, C, s, zb, W1b, B2b, Hb);
    gemm1_relu<<<dim3(BB / 256, DH / 128), 512, 0, stream>>>(zb, W1b, h1, Hb);
    gemm2_out<<<dim3(BB / 128, DZ / 128), 256, 0, stream>>>(Hb, B2b, A, h2, z, out);
}